// Round 4
// baseline (226.385 us; speedup 1.0000x reference)
//
#include <hip/hip_runtime.h>
#include <math.h>

#define NE 64
#define NTASK 6
#define BLK 256
#define GRID 2048
#define RPW 16      // rows per wave-iteration (4 lanes per row)

typedef float nfloat4 __attribute__((ext_vector_type(4)));

// ---------------------------------------------------------------------------
// Kernel A: per-task precompute (6 x 64 tables) in f64. Layout [t][e] (t padded
// to 8): tab_f float2 pairs {cl,ns}, tab_d double2. Also zeroes `load`.
// ---------------------------------------------------------------------------
__global__ void precompute_kernel(
    const float* __restrict__ embed_table,   // (6,32)
    const float* __restrict__ expert_keys,   // (32,32)
    const float* __restrict__ in_proj_w,     // (96,32)
    const float* __restrict__ in_proj_b,     // (96,)
    const float* __restrict__ fc_gate_w,     // (64,32)
    const float* __restrict__ fc_gate_b,     // (64,)
    const float* __restrict__ fc_noise_w,    // (64,32)
    const float* __restrict__ fc_noise_b,    // (64,)
    float*   __restrict__ tab_f,             // 1024 floats  [t*64+e]*2
    double2* __restrict__ tab_d,             // 512 double2  [t*64+e]
    float*   __restrict__ load)              // (64,) zero-init
{
    __shared__ double Ksh[32][32];
    __shared__ double Qsh[6][32];
    __shared__ double sc[24][32];
    __shared__ double attn[6][32];
    __shared__ double ew[6][32];
    __shared__ double red[24];
    __shared__ double red2[6];
    const int tid = threadIdx.x;

    if (tid < NE) load[tid] = 0.f;

    for (int idx = tid; idx < 32 * 32; idx += BLK) {
        int s = idx >> 5, j = idx & 31;
        double acc = (double)in_proj_b[32 + j];
        for (int d = 0; d < 32; ++d)
            acc += (double)expert_keys[s * 32 + d] * (double)in_proj_w[(32 + j) * 32 + d];
        Ksh[s][j] = acc;
    }
    for (int idx = tid; idx < NTASK * 32; idx += BLK) {
        int t = idx >> 5, j = idx & 31;
        double acc = (double)in_proj_b[j];
        for (int d = 0; d < 32; ++d)
            acc += (double)embed_table[t * 32 + d] * (double)in_proj_w[j * 32 + d];
        Qsh[t][j] = acc;
    }
    __syncthreads();

    const double SCALE = 1.0 / (double)((float)2.8284271247461903);
    for (int idx = tid; idx < 24 * 32; idx += BLK) {
        int th = idx >> 5, s = idx & 31;
        int t = th >> 2, h = th & 3;
        double acc = 0.0;
        for (int d = 0; d < 8; ++d)
            acc += Qsh[t][h * 8 + d] * Ksh[s][h * 8 + d];
        sc[th][s] = acc * SCALE;
    }
    __syncthreads();
    if (tid < 24) {
        double m = sc[tid][0];
        for (int s = 1; s < 32; ++s) m = fmax(m, sc[tid][s]);
        red[tid] = m;
    }
    __syncthreads();
    for (int idx = tid; idx < 24 * 32; idx += BLK) {
        int th = idx >> 5, s = idx & 31;
        sc[th][s] = exp(sc[th][s] - red[th]);
    }
    __syncthreads();
    if (tid < 24) {
        double sum = 0.0;
        for (int s = 0; s < 32; ++s) sum += sc[tid][s];
        red[tid] = 1.0 / sum;
    }
    __syncthreads();
    for (int idx = tid; idx < NTASK * 32; idx += BLK) {
        int t = idx >> 5, s = idx & 31;
        attn[t][s] = 0.25 * (sc[t*4+0][s]*red[t*4+0] + sc[t*4+1][s]*red[t*4+1]
                           + sc[t*4+2][s]*red[t*4+2] + sc[t*4+3][s]*red[t*4+3]);
    }
    __syncthreads();
    if (tid < NTASK) {
        double m = attn[tid][0];
        for (int s = 1; s < 32; ++s) m = fmax(m, attn[tid][s]);
        red2[tid] = m;
    }
    __syncthreads();
    for (int idx = tid; idx < NTASK * 32; idx += BLK) {
        int t = idx >> 5, s = idx & 31;
        ew[t][s] = exp(attn[t][s] - red2[t]);
    }
    __syncthreads();
    if (tid < NTASK) {
        double sum = 0.0;
        for (int s = 0; s < 32; ++s) sum += ew[tid][s];
        red2[tid] = 1.0 / sum;
    }
    __syncthreads();

    for (int idx = tid; idx < NTASK * NE; idx += BLK) {
        int t = idx >> 6, e = idx & 63;
        double inv = red2[t];
        double a  = (double)fc_gate_b[e];
        double n0 = (double)fc_noise_b[e];
        for (int d = 0; d < 32; ++d) {
            double w = ew[t][d] * inv;
            a  += w * (double)fc_gate_w [e * 32 + d];
            n0 += w * (double)fc_noise_w[e * 32 + d];
        }
        double sp = (n0 > 0.0) ? (n0 + log1p(exp(-n0))) : log1p(exp(n0));
        double ns = sp + 0.01;
        const int o = t * 64 + e;
        tab_f[o * 2 + 0] = (float)a;
        tab_f[o * 2 + 1] = (float)ns;
        tab_d[o] = make_double2(a, ns);
    }
    for (int idx = tid; idx < 512; idx += BLK) {
        if ((idx >> 6) >= NTASK) {
            tab_f[idx * 2 + 0] = 0.f;
            tab_f[idx * 2 + 1] = 0.f;
            tab_d[idx] = make_double2(0.0, 0.0);
        }
    }
}

// ---------------------------------------------------------------------------
// Kernel B: 4 lanes per row, no noise staging, no in-loop barriers.
// Lane (sub=lane>>2, c=lane&3) owns experts [c*16, c*16+16) of row g*16+sub.
// ---------------------------------------------------------------------------
__global__ __launch_bounds__(BLK) void router_kernel(
    const int*     __restrict__ taskID,
    const float4*  __restrict__ noise4,   // (B*16)
    const float4*  __restrict__ tabf4,    // 256 float4 = 512 {cl,ns} float2
    const double2* __restrict__ tabd,     // 512
    float* __restrict__ gates,            // (B*64)
    float* __restrict__ load,             // (64,)
    int B)
{
    __shared__ float4  s_tabf4[256];   // 4 KB, XOR-swizzled at 16B granularity
    __shared__ double2 s_tabd[512];    // 8 KB
    __shared__ float   s_load[NE];

    const int tid = threadIdx.x;
    for (int i = tid; i < 256; i += BLK) {
        const int tt = i >> 5, cc = (i >> 3) & 3, rr = i & 7;
        const int dst = (i & ~7) | (rr ^ ((2 * cc + tt) & 7));
        s_tabf4[dst] = tabf4[i];
    }
    for (int i = tid; i < 512; i += BLK) s_tabd[i] = tabd[i];
    if (tid < NE) s_load[tid] = 0.f;
    __syncthreads();

    const int lane  = tid & 63;
    const int sub   = lane >> 2;
    const int c     = lane & 3;
    const int ebase = c * 16;
    const int W = (blockIdx.x * BLK + tid) >> 6;
    const int nWaves = GRID * (BLK / 64);
    const int nGroup = (B + RPW - 1) / RPW;

    for (int g = W; g < nGroup; g += nWaves) {
        const int row = g * RPW + sub;
        const bool ok = row < B;
        int t = 0;
        if (ok) t = taskID[row];
        const int nb = row * 16 + c * 4;
        float4 nz0, nz1, nz2, nz3;
        if (ok) {
            nz0 = noise4[nb + 0]; nz1 = noise4[nb + 1];
            nz2 = noise4[nb + 2]; nz3 = noise4[nb + 3];
        } else {
            nz0 = nz1 = nz2 = nz3 = make_float4(0.f, 0.f, 0.f, 0.f);
        }

        const int x  = (2 * c + t) & 7;
        const int tb = t * 32 + c * 8;

        float v1 = -INFINITY, v2 = -INFINITY, v3 = -INFINITY;
        int   i1 = 0, i2 = 0, i3 = 0;
        float n1 = 0.f, n2 = 0.f, n3 = 0.f;

#define INS(l_, e_, n_) {                                                      \
        const bool b1 = (l_) > v1, b2 = (l_) > v2, b3 = (l_) > v3;             \
        v3 = b2 ? v2 : (b3 ? (l_) : v3);                                       \
        i3 = b2 ? i2 : (b3 ? (e_) : i3);                                       \
        n3 = b2 ? n2 : (b3 ? (n_) : n3);                                       \
        v2 = b1 ? v1 : (b2 ? (l_) : v2);                                       \
        i2 = b1 ? i1 : (b2 ? (e_) : i2);                                       \
        n2 = b1 ? n1 : (b2 ? (n_) : n2);                                       \
        v1 = b1 ? (l_) : v1;                                                   \
        i1 = b1 ? (e_) : i1;                                                   \
        n1 = b1 ? (n_) : n1; }

#define STEP(r_, nlo_, nhi_) {                                                 \
        const float4 tv = s_tabf4[tb + ((r_) ^ x)];                            \
        const float l0 = __fadd_rn(tv.x, __fmul_rn((nlo_), tv.y));             \
        const float l1 = __fadd_rn(tv.z, __fmul_rn((nhi_), tv.w));             \
        INS(l0, ebase + 2 * (r_),     (nlo_));                                 \
        INS(l1, ebase + 2 * (r_) + 1, (nhi_)); }

        STEP(0, nz0.x, nz0.y); STEP(1, nz0.z, nz0.w);
        STEP(2, nz1.x, nz1.y); STEP(3, nz1.z, nz1.w);
        STEP(4, nz2.x, nz2.y); STEP(5, nz2.z, nz2.w);
        STEP(6, nz3.x, nz3.y); STEP(7, nz3.z, nz3.w);
#undef STEP
#undef INS

        // 2-step butterfly merge of sorted triples across the 4 lanes of the row
        #pragma unroll
        for (int m = 1; m <= 2; m <<= 1) {
            const float w1 = __shfl_xor(v1, m), w2 = __shfl_xor(v2, m), w3 = __shfl_xor(v3, m);
            const int   j1 = __shfl_xor(i1, m), j2 = __shfl_xor(i2, m), j3 = __shfl_xor(i3, m);
            const float q1 = __shfl_xor(n1, m), q2 = __shfl_xor(n2, m), q3 = __shfl_xor(n3, m);
            const bool aw = (v1 > w1) || (v1 == w1 && i1 < j1);
            const float p1 = aw ? v1 : w1, p2 = aw ? v2 : w2, p3 = aw ? v3 : w3;
            const int   pi1 = aw ? i1 : j1, pi2 = aw ? i2 : j2, pi3 = aw ? i3 : j3;
            const float pn1 = aw ? n1 : q1, pn2 = aw ? n2 : q2, pn3 = aw ? n3 : q3;
            const float u1 = aw ? w1 : v1, u2 = aw ? w2 : v2;
            const int   ui1 = aw ? j1 : i1, ui2 = aw ? j2 : i2;
            const float un1 = aw ? q1 : n1, un2 = aw ? q2 : n2;
            const bool b2 = (p2 > u1) || (p2 == u1 && pi2 < ui1);
            const bool b3a = (p3 > u1) || (p3 == u1 && pi3 < ui1);
            const bool b3b = (p2 > u2) || (p2 == u2 && pi2 < ui2);
            v1 = p1;  i1 = pi1; n1 = pn1;
            v2 = b2 ? p2 : u1;  i2 = b2 ? pi2 : ui1;  n2 = b2 ? pn2 : un1;
            v3 = b2 ? (b3a ? p3 : u1) : (b3b ? p2 : u2);
            i3 = b2 ? (b3a ? pi3 : ui1) : (b3b ? pi2 : ui2);
            n3 = b2 ? (b3a ? pn3 : un1) : (b3b ? pn2 : un2);
        }

        // f64 refine of the top-3 (all 4 lanes redundantly; LDS broadcast)
        const double2 A = s_tabd[t * 64 + i1];
        const double2 Bt = s_tabd[t * 64 + i2];
        const double2 Ct = s_tabd[t * 64 + i3];
        double da = A.x  + (double)n1 * A.y;  int ia = i1;
        double db = Bt.x + (double)n2 * Bt.y; int ib = i2;
        double dc = Ct.x + (double)n3 * Ct.y; int ic = i3;
        if (db > da || (db == da && ib < ia)) { double tv = da; da = db; db = tv; int ti = ia; ia = ib; ib = ti; }
        if (dc > da || (dc == da && ic < ia)) { double tv = da; da = dc; dc = tv; int ti = ia; ia = ic; ic = ti; }
        if (dc > db || (dc == db && ic < ib)) { double tv = db; db = dc; dc = tv; int ti = ib; ib = ic; ic = ti; }

        const double e2 = exp(db - da);
        const double denom = 1.0 + e2;
        const float g1 = (float)(1.0 / denom);
        const float g2 = (float)(e2 / denom);

        if (ok) {
            nfloat4* gdst = (nfloat4*)(gates + (size_t)nb * 4);
            #pragma unroll
            for (int k = 0; k < 4; ++k) {
                const int e0 = ebase + 4 * k;
                nfloat4 w;
                w.x = (e0 + 0 == ia) ? g1 : ((e0 + 0 == ib) ? g2 : 0.f);
                w.y = (e0 + 1 == ia) ? g1 : ((e0 + 1 == ib) ? g2 : 0.f);
                w.z = (e0 + 2 == ia) ? g1 : ((e0 + 2 == ib) ? g2 : 0.f);
                w.w = (e0 + 3 == ia) ? g1 : ((e0 + 3 == ib) ? g2 : 0.f);
                __builtin_nontemporal_store(w, gdst + k);
            }
            if (c == 0) {
                atomicAdd(&s_load[ia], g1);
                atomicAdd(&s_load[ib], g2);
            }
        }
    }
    __syncthreads();
    if (tid < NE) atomicAdd(&load[tid], s_load[tid]);
}

// ---------------------------------------------------------------------------
extern "C" void kernel_launch(void* const* d_in, const int* in_sizes, int n_in,
                              void* d_out, int out_size, void* d_ws, size_t ws_size,
                              hipStream_t stream) {
    const int*   taskID      = (const int*)  d_in[0];
    const float* embed_table = (const float*)d_in[1];
    const float* expert_keys = (const float*)d_in[2];
    const float* in_proj_w   = (const float*)d_in[3];
    const float* in_proj_b   = (const float*)d_in[4];
    const float* fc_gate_w   = (const float*)d_in[5];
    const float* fc_gate_b   = (const float*)d_in[6];
    const float* fc_noise_w  = (const float*)d_in[7];
    const float* fc_noise_b  = (const float*)d_in[8];
    const float* noise       = (const float*)d_in[9];

    const int B = in_sizes[0];

    float*   tab_f = (float*)d_ws;                    // 4 KB
    double2* tab_d = (double2*)((char*)d_ws + 4096);  // 8 KB

    float* gates = (float*)d_out;
    float* load  = gates + (size_t)B * NE;

    precompute_kernel<<<1, BLK, 0, stream>>>(embed_table, expert_keys, in_proj_w, in_proj_b,
                                             fc_gate_w, fc_gate_b, fc_noise_w, fc_noise_b,
                                             tab_f, tab_d, load);

    router_kernel<<<GRID, BLK, 0, stream>>>(taskID, (const float4*)noise,
                                            (const float4*)tab_f, tab_d,
                                            gates, load, B);
}

// Round 5
// 114.186 us; speedup vs baseline: 1.9826x; 1.9826x over previous
//
#include <hip/hip_runtime.h>
#include <math.h>

#define NE 64
#define NTASK 6
#define BLK 256
#define GRID 1024
#define RPW 16      // rows per wave-iteration (4 lanes per row)

// ---------------------------------------------------------------------------
// Kernel A: per-task precompute (6 x 64 tables) in f64. Layout [t][e] (t padded
// to 8): tab_f float2 pairs {cl,ns}, tab_d double2. Also zeroes `load`.
// ---------------------------------------------------------------------------
__global__ void precompute_kernel(
    const float* __restrict__ embed_table,   // (6,32)
    const float* __restrict__ expert_keys,   // (32,32)
    const float* __restrict__ in_proj_w,     // (96,32)
    const float* __restrict__ in_proj_b,     // (96,)
    const float* __restrict__ fc_gate_w,     // (64,32)
    const float* __restrict__ fc_gate_b,     // (64,)
    const float* __restrict__ fc_noise_w,    // (64,32)
    const float* __restrict__ fc_noise_b,    // (64,)
    float*   __restrict__ tab_f,             // 1024 floats  [t*64+e]*2
    double2* __restrict__ tab_d,             // 512 double2  [t*64+e]
    float*   __restrict__ load)              // (64,) zero-init
{
    __shared__ double Ksh[32][32];
    __shared__ double Qsh[6][32];
    __shared__ double sc[24][32];
    __shared__ double attn[6][32];
    __shared__ double ew[6][32];
    __shared__ double red[24];
    __shared__ double red2[6];
    const int tid = threadIdx.x;

    if (tid < NE) load[tid] = 0.f;

    for (int idx = tid; idx < 32 * 32; idx += BLK) {
        int s = idx >> 5, j = idx & 31;
        double acc = (double)in_proj_b[32 + j];
        for (int d = 0; d < 32; ++d)
            acc += (double)expert_keys[s * 32 + d] * (double)in_proj_w[(32 + j) * 32 + d];
        Ksh[s][j] = acc;
    }
    for (int idx = tid; idx < NTASK * 32; idx += BLK) {
        int t = idx >> 5, j = idx & 31;
        double acc = (double)in_proj_b[j];
        for (int d = 0; d < 32; ++d)
            acc += (double)embed_table[t * 32 + d] * (double)in_proj_w[j * 32 + d];
        Qsh[t][j] = acc;
    }
    __syncthreads();

    const double SCALE = 1.0 / (double)((float)2.8284271247461903);
    for (int idx = tid; idx < 24 * 32; idx += BLK) {
        int th = idx >> 5, s = idx & 31;
        int t = th >> 2, h = th & 3;
        double acc = 0.0;
        for (int d = 0; d < 8; ++d)
            acc += Qsh[t][h * 8 + d] * Ksh[s][h * 8 + d];
        sc[th][s] = acc * SCALE;
    }
    __syncthreads();
    if (tid < 24) {
        double m = sc[tid][0];
        for (int s = 1; s < 32; ++s) m = fmax(m, sc[tid][s]);
        red[tid] = m;
    }
    __syncthreads();
    for (int idx = tid; idx < 24 * 32; idx += BLK) {
        int th = idx >> 5, s = idx & 31;
        sc[th][s] = exp(sc[th][s] - red[th]);
    }
    __syncthreads();
    if (tid < 24) {
        double sum = 0.0;
        for (int s = 0; s < 32; ++s) sum += sc[tid][s];
        red[tid] = 1.0 / sum;
    }
    __syncthreads();
    for (int idx = tid; idx < NTASK * 32; idx += BLK) {
        int t = idx >> 5, s = idx & 31;
        attn[t][s] = 0.25 * (sc[t*4+0][s]*red[t*4+0] + sc[t*4+1][s]*red[t*4+1]
                           + sc[t*4+2][s]*red[t*4+2] + sc[t*4+3][s]*red[t*4+3]);
    }
    __syncthreads();
    if (tid < NTASK) {
        double m = attn[tid][0];
        for (int s = 1; s < 32; ++s) m = fmax(m, attn[tid][s]);
        red2[tid] = m;
    }
    __syncthreads();
    for (int idx = tid; idx < NTASK * 32; idx += BLK) {
        int t = idx >> 5, s = idx & 31;
        ew[t][s] = exp(attn[t][s] - red2[t]);
    }
    __syncthreads();
    if (tid < NTASK) {
        double sum = 0.0;
        for (int s = 0; s < 32; ++s) sum += ew[tid][s];
        red2[tid] = 1.0 / sum;
    }
    __syncthreads();

    for (int idx = tid; idx < NTASK * NE; idx += BLK) {
        int t = idx >> 6, e = idx & 63;
        double inv = red2[t];
        double a  = (double)fc_gate_b[e];
        double n0 = (double)fc_noise_b[e];
        for (int d = 0; d < 32; ++d) {
            double w = ew[t][d] * inv;
            a  += w * (double)fc_gate_w [e * 32 + d];
            n0 += w * (double)fc_noise_w[e * 32 + d];
        }
        double sp = (n0 > 0.0) ? (n0 + log1p(exp(-n0))) : log1p(exp(n0));
        double ns = sp + 0.01;
        const int o = t * 64 + e;
        tab_f[o * 2 + 0] = (float)a;
        tab_f[o * 2 + 1] = (float)ns;
        tab_d[o] = make_double2(a, ns);
    }
    for (int idx = tid; idx < 512; idx += BLK) {
        if ((idx >> 6) >= NTASK) {
            tab_f[idx * 2 + 0] = 0.f;
            tab_f[idx * 2 + 1] = 0.f;
            tab_d[idx] = make_double2(0.0, 0.0);
        }
    }
}

// ---------------------------------------------------------------------------
// Kernel B: 4 lanes per row, register-double-buffered grid-stride loop.
// Lane (sub=lane>>2, c=lane&3) owns experts [c*16, c*16+16) of row g*16+sub.
// ---------------------------------------------------------------------------
__global__ __launch_bounds__(BLK) void router_kernel(
    const int*     __restrict__ taskID,
    const float4*  __restrict__ noise4,   // (B*16)
    const float4*  __restrict__ tabf4,    // 256 float4 = 512 {cl,ns} float2
    const double2* __restrict__ tabd,     // 512
    float4* __restrict__ gates4,          // (B*16)
    float*  __restrict__ load,            // (64,)
    int B)
{
    __shared__ float4  s_tabf4[256];   // 4 KB, XOR-swizzled at 16B granularity
    __shared__ double2 s_tabd[512];    // 8 KB
    __shared__ float   s_load[NE];

    const int tid = threadIdx.x;
    for (int i = tid; i < 256; i += BLK) {
        const int tt = i >> 5, cc = (i >> 3) & 3, rr = i & 7;
        const int dst = (i & ~7) | (rr ^ ((2 * cc + tt) & 7));
        s_tabf4[dst] = tabf4[i];
    }
    for (int i = tid; i < 512; i += BLK) s_tabd[i] = tabd[i];
    if (tid < NE) s_load[tid] = 0.f;
    __syncthreads();

    const int lane  = tid & 63;
    const int sub   = lane >> 2;
    const int c     = lane & 3;
    const int ebase = c * 16;
    const int W = (blockIdx.x * BLK + tid) >> 6;
    const int nWaves = GRID * (BLK / 64);
    const int nGroup = (B + RPW - 1) / RPW;

    // ---- preload first group ----
    int   tc = 0;
    float4 a0, a1, a2, a3;
    a0 = a1 = a2 = a3 = make_float4(0.f, 0.f, 0.f, 0.f);
    bool okc = false;
    int  rowc = 0;
    if (W < nGroup) {
        rowc = W * RPW + sub;
        okc = rowc < B;
        if (okc) {
            tc = taskID[rowc];
            const int nb = rowc * 16 + c * 4;
            a0 = noise4[nb + 0]; a1 = noise4[nb + 1];
            a2 = noise4[nb + 2]; a3 = noise4[nb + 3];
        }
    }

    for (int g = W; g < nGroup; g += nWaves) {
        // ---- issue next group's loads (prefetch) ----
        const int gn = g + nWaves;
        int   tn = 0;
        float4 b0, b1, b2, b3;
        b0 = b1 = b2 = b3 = make_float4(0.f, 0.f, 0.f, 0.f);
        bool okn = false;
        int  rown = 0;
        if (gn < nGroup) {
            rown = gn * RPW + sub;
            okn = rown < B;
            if (okn) {
                tn = taskID[rown];
                const int nb = rown * 16 + c * 4;
                b0 = noise4[nb + 0]; b1 = noise4[nb + 1];
                b2 = noise4[nb + 2]; b3 = noise4[nb + 3];
            }
        }

        // ---- process current group ----
        const int t  = tc;
        const int x  = (2 * c + t) & 7;
        const int tb = t * 32 + c * 8;

        float v1 = -INFINITY, v2 = -INFINITY, v3 = -INFINITY;
        int   i1 = 0, i2 = 0, i3 = 0;
        float n1 = 0.f, n2 = 0.f, n3 = 0.f;

#define INS(l_, e_, n_) {                                                      \
        const bool b1_ = (l_) > v1, b2_ = (l_) > v2, b3_ = (l_) > v3;          \
        v3 = b2_ ? v2 : (b3_ ? (l_) : v3);                                     \
        i3 = b2_ ? i2 : (b3_ ? (e_) : i3);                                     \
        n3 = b2_ ? n2 : (b3_ ? (n_) : n3);                                     \
        v2 = b1_ ? v1 : (b2_ ? (l_) : v2);                                     \
        i2 = b1_ ? i1 : (b2_ ? (e_) : i2);                                     \
        n2 = b1_ ? n1 : (b2_ ? (n_) : n2);                                     \
        v1 = b1_ ? (l_) : v1;                                                  \
        i1 = b1_ ? (e_) : i1;                                                  \
        n1 = b1_ ? (n_) : n1; }

#define STEP(r_, nlo_, nhi_) {                                                 \
        const float4 tv = s_tabf4[tb + ((r_) ^ x)];                            \
        const float l0 = __fadd_rn(tv.x, __fmul_rn((nlo_), tv.y));             \
        const float l1 = __fadd_rn(tv.z, __fmul_rn((nhi_), tv.w));             \
        INS(l0, ebase + 2 * (r_),     (nlo_));                                 \
        INS(l1, ebase + 2 * (r_) + 1, (nhi_)); }

        STEP(0, a0.x, a0.y); STEP(1, a0.z, a0.w);
        STEP(2, a1.x, a1.y); STEP(3, a1.z, a1.w);
        STEP(4, a2.x, a2.y); STEP(5, a2.z, a2.w);
        STEP(6, a3.x, a3.y); STEP(7, a3.z, a3.w);
#undef STEP
#undef INS

        // 2-step butterfly merge of sorted triples across the 4 lanes of the row
        #pragma unroll
        for (int m = 1; m <= 2; m <<= 1) {
            const float w1 = __shfl_xor(v1, m), w2 = __shfl_xor(v2, m), w3 = __shfl_xor(v3, m);
            const int   j1 = __shfl_xor(i1, m), j2 = __shfl_xor(i2, m), j3 = __shfl_xor(i3, m);
            const float q1 = __shfl_xor(n1, m), q2 = __shfl_xor(n2, m), q3 = __shfl_xor(n3, m);
            const bool aw = (v1 > w1) || (v1 == w1 && i1 < j1);
            const float p1 = aw ? v1 : w1, p2 = aw ? v2 : w2, p3 = aw ? v3 : w3;
            const int   pi1 = aw ? i1 : j1, pi2 = aw ? i2 : j2, pi3 = aw ? i3 : j3;
            const float pn1 = aw ? n1 : q1, pn2 = aw ? n2 : q2, pn3 = aw ? n3 : q3;
            const float u1 = aw ? w1 : v1, u2 = aw ? w2 : v2;
            const int   ui1 = aw ? j1 : i1, ui2 = aw ? j2 : i2;
            const float un1 = aw ? q1 : n1, un2 = aw ? q2 : n2;
            const bool b2 = (p2 > u1) || (p2 == u1 && pi2 < ui1);
            const bool b3a = (p3 > u1) || (p3 == u1 && pi3 < ui1);
            const bool b3b = (p2 > u2) || (p2 == u2 && pi2 < ui2);
            v1 = p1;  i1 = pi1; n1 = pn1;
            v2 = b2 ? p2 : u1;  i2 = b2 ? pi2 : ui1;  n2 = b2 ? pn2 : un1;
            v3 = b2 ? (b3a ? p3 : u1) : (b3b ? p2 : u2);
            i3 = b2 ? (b3a ? pi3 : ui1) : (b3b ? pi2 : ui2);
            n3 = b2 ? (b3a ? pn3 : un1) : (b3b ? pn2 : un2);
        }

        // f64 refine of the top-3 (all 4 lanes redundantly; LDS broadcast)
        const double2 A  = s_tabd[t * 64 + i1];
        const double2 Bt = s_tabd[t * 64 + i2];
        const double2 Ct = s_tabd[t * 64 + i3];
        double da = A.x  + (double)n1 * A.y;  int ia = i1;
        double db = Bt.x + (double)n2 * Bt.y; int ib = i2;
        double dc = Ct.x + (double)n3 * Ct.y; int ic = i3;
        if (db > da || (db == da && ib < ia)) { double tv = da; da = db; db = tv; int ti = ia; ia = ib; ib = ti; }
        if (dc > da || (dc == da && ic < ia)) { double tv = da; da = dc; dc = tv; int ti = ia; ia = ic; ic = ti; }
        if (dc > db || (dc == db && ic < ib)) { double tv = db; db = dc; dc = tv; int ti = ib; ib = ic; ic = ti; }

        // 2-way softmax: ordering already fixed; f32 exp is plenty (≤2 ulp)
        const float e2 = expf((float)(db - da));
        const float g1 = 1.0f / (1.0f + e2);
        const float g2 = e2 / (1.0f + e2);

        if (okc) {
            const int nb = rowc * 16 + c * 4;
            #pragma unroll
            for (int k = 0; k < 4; ++k) {
                const int e0 = ebase + 4 * k;
                float4 w;
                w.x = (e0 + 0 == ia) ? g1 : ((e0 + 0 == ib) ? g2 : 0.f);
                w.y = (e0 + 1 == ia) ? g1 : ((e0 + 1 == ib) ? g2 : 0.f);
                w.z = (e0 + 2 == ia) ? g1 : ((e0 + 2 == ib) ? g2 : 0.f);
                w.w = (e0 + 3 == ia) ? g1 : ((e0 + 3 == ib) ? g2 : 0.f);
                gates4[nb + k] = w;
            }
            if (c == 0) {
                atomicAdd(&s_load[ia], g1);
                atomicAdd(&s_load[ib], g2);
            }
        }

        // ---- rotate double buffer ----
        tc = tn; rowc = rown; okc = okn;
        a0 = b0; a1 = b1; a2 = b2; a3 = b3;
    }
    __syncthreads();
    if (tid < NE) atomicAdd(&load[tid], s_load[tid]);
}

// ---------------------------------------------------------------------------
extern "C" void kernel_launch(void* const* d_in, const int* in_sizes, int n_in,
                              void* d_out, int out_size, void* d_ws, size_t ws_size,
                              hipStream_t stream) {
    const int*   taskID      = (const int*)  d_in[0];
    const float* embed_table = (const float*)d_in[1];
    const float* expert_keys = (const float*)d_in[2];
    const float* in_proj_w   = (const float*)d_in[3];
    const float* in_proj_b   = (const float*)d_in[4];
    const float* fc_gate_w   = (const float*)d_in[5];
    const float* fc_gate_b   = (const float*)d_in[6];
    const float* fc_noise_w  = (const float*)d_in[7];
    const float* fc_noise_b  = (const float*)d_in[8];
    const float* noise       = (const float*)d_in[9];

    const int B = in_sizes[0];

    float*   tab_f = (float*)d_ws;                    // 4 KB
    double2* tab_d = (double2*)((char*)d_ws + 4096);  // 8 KB

    float* gates = (float*)d_out;
    float* load  = gates + (size_t)B * NE;

    precompute_kernel<<<1, BLK, 0, stream>>>(embed_table, expert_keys, in_proj_w, in_proj_b,
                                             fc_gate_w, fc_gate_b, fc_noise_w, fc_noise_b,
                                             tab_f, tab_d, load);

    router_kernel<<<GRID, BLK, 0, stream>>>(taskID, (const float4*)noise,
                                            (const float4*)tab_f, tab_d,
                                            (float4*)gates, load, B);
}